// Round 6
// baseline (153.345 us; speedup 1.0000x reference)
//
#include <hip/hip_runtime.h>
#include <math.h>

#define HD    128
#define NQH   32
#define NKVH  8
#define GQA   4
#define PBLK  16      // paged cache block size
#define MAXNB 512     // max block-table entries cached in LDS
#define SCMAX 512     // max tokens per score chunk staged in LDS

typedef float f4 __attribute__((ext_vector_type(4)));
typedef float f2 __attribute__((ext_vector_type(2)));

// token base pointer (K or V) for token t; t == T means "current" k/v
__device__ __forceinline__ const float* tok_base(
    const float* __restrict__ cache, const float* __restrict__ cur,
    const int* __restrict__ btrow, int t, int T, int b, int h)
{
    if (t == T) return cur + ((size_t)b * NKVH + h) * HD;
    int blk = btrow[t >> 4];
    return cache + (((size_t)blk * PBLK + (t & (PBLK - 1))) * NKVH + h) * HD;
}

// interleaved rope table: tab[t*128 + 2*f] = cos(t*invf[f]), [2*f+1] = sin
__global__ void rope_table_kernel(float* __restrict__ tab, int T) {
    int idx = blockIdx.x * blockDim.x + threadIdx.x;
    int total = (T + 1) * 64;
    if (idx >= total) return;
    int t = idx >> 6;
    int f = idx & 63;
    double ang = (double)t * pow(10000.0, -(double)f / 64.0);
    tab[(size_t)t * 128 + 2 * f]     = (float)cos(ang);
    tab[(size_t)t * 128 + 2 * f + 1] = (float)sin(ang);
}

// Phase-split flash-decode: scores -> LDS (independent iters, deep pipelining),
// block softmax, then PV accumulation. Removes the per-token serial
// shuffle+online-softmax chain that latency-bound rounds 2-5 (170us @ 35% VALU).
__global__ __launch_bounds__(256) void paged_attn_kernel(
    const float* __restrict__ q,
    const float* __restrict__ kcur,
    const float* __restrict__ vcur,
    const float* __restrict__ kc,
    const float* __restrict__ vc,
    const int* __restrict__ bt,
    const float* __restrict__ tab,
    float* __restrict__ out,       // used when S == 1
    float* __restrict__ pm,        // [nblk][4]
    float* __restrict__ pl,        // [nblk][4]
    float* __restrict__ po,        // [nblk][4][HD]
    int T, int nb, int S, int useTable)
{
    const int bh = blockIdx.x / S;
    const int s  = blockIdx.x - bh * S;
    const int b  = bh >> 3;
    const int h  = bh & 7;
    const int tid = threadIdx.x;
    const int hw  = tid >> 5;        // half-wave id 0..7
    const int il  = tid & 31;        // lane within half-wave
    const int d0v = il << 2;         // V/output dims [d0v, d0v+4)
    const int dk  = il << 1;         // K dims: {dk,dk+1} and {64+dk, 64+dk+1}
    const int w   = tid >> 6;        // wave id 0..3

    const int total = T + 1;
    const int chunkT = (total + S - 1) / S;
    const int lo0   = s * chunkT;
    const int hi0   = min(lo0 + chunkT, total);

    __shared__ int   sbt[MAXNB];
    __shared__ float sc[SCMAX * 4];          // scores / p for current chunk, [t][g]
    __shared__ float redM[4][4];             // per-wave max partials [wave][g]
    __shared__ float redL[4][4];             // per-wave sum partials [wave][g]
    __shared__ float lodata[4][4][HD];       // final per-wave o partials

    // cache block table row in LDS
    const int* btrow = bt + (size_t)b * nb;
    if (nb <= MAXNB) {
        for (int i = tid; i < nb; i += 256) sbt[i] = btrow[i];
        __syncthreads();
        btrow = sbt;
    }

    float invf0 = 0.f, invf1 = 0.f;
    if (!useTable) {
        invf0 = exp2f(-(float)(dk)     * (13.287712379549449f / 64.0f));
        invf1 = exp2f(-(float)(dk + 1) * (13.287712379549449f / 64.0f));
    }

    const float scale = 0.08838834764831845f;  // 128^-0.5

    // --- rope current q (4 GQA heads) at position T, scale folded in ---
    f4 qr[4];
    {
        f4 cs;
        if (useTable) {
            cs = *(const f4*)(tab + (size_t)T * 128 + 4 * il);
        } else {
            float ss, cc;
            sincosf((float)T * invf0, &ss, &cc); cs.x = cc; cs.y = ss;
            sincosf((float)T * invf1, &ss, &cc); cs.z = cc; cs.w = ss;
        }
        const float* qb = q + ((size_t)b * NQH + h * GQA) * HD;
#pragma unroll
        for (int g = 0; g < 4; ++g) {
            f2 xlo = *(const f2*)(qb + (size_t)g * HD + dk);
            f2 xhi = *(const f2*)(qb + (size_t)g * HD + 64 + dk);
            qr[g].x = (xlo.x * cs.x - xhi.x * cs.y) * scale;
            qr[g].y = (xlo.y * cs.z - xhi.y * cs.w) * scale;
            qr[g].z = (xhi.x * cs.x + xlo.x * cs.y) * scale;
            qr[g].w = (xhi.y * cs.z + xlo.y * cs.w) * scale;
        }
    }

    // running state (redundant identical copies in every thread)
    float Mr0 = -INFINITY, Mr1 = -INFINITY, Mr2 = -INFINITY, Mr3 = -INFINITY;
    float Lr0 = 0.f, Lr1 = 0.f, Lr2 = 0.f, Lr3 = 0.f;
    f4 o[4] = {};

    const int gsm  = tid & 3;        // head for softmax-reduce phase
    const int idxm = tid >> 2;       // 0..63

    for (int clo = lo0; clo < hi0; clo += SCMAX) {
        const int chi = min(clo + SCMAX, hi0);
        const int cn  = chi - clo;

        // ================= phase 1: raw scores -> LDS =================
        {
            int t = clo + hw;
            f2 klo = {}, khi = {};
            f4 cs = {};
            if (t < chi) {
                const float* kb = tok_base(kc, kcur, btrow, t, T, b, h);
                klo = *(const f2*)(kb + dk);
                khi = *(const f2*)(kb + 64 + dk);
                if (useTable) cs = *(const f4*)(tab + (size_t)t * 128 + 4 * il);
            }
            for (; t < chi; t += 8) {
                const int tn = t + 8;
                f2 klon = {}, khin = {};
                f4 csn = {};
                if (tn < chi) {
                    const float* kb = tok_base(kc, kcur, btrow, tn, T, b, h);
                    klon = *(const f2*)(kb + dk);
                    khin = *(const f2*)(kb + 64 + dk);
                    if (useTable) csn = *(const f4*)(tab + (size_t)tn * 128 + 4 * il);
                }
                if (!useTable) {
                    float ss, cc;
                    sincosf((float)t * invf0, &ss, &cc); cs.x = cc; cs.y = ss;
                    sincosf((float)t * invf1, &ss, &cc); cs.z = cc; cs.w = ss;
                }
                f4 kr;
                kr.x = klo.x * cs.x - khi.x * cs.y;
                kr.y = klo.y * cs.z - khi.y * cs.w;
                kr.z = khi.x * cs.x + klo.x * cs.y;
                kr.w = khi.y * cs.z + klo.y * cs.w;

                float s0 = qr[0].x * kr.x + qr[0].y * kr.y + qr[0].z * kr.z + qr[0].w * kr.w;
                float s1 = qr[1].x * kr.x + qr[1].y * kr.y + qr[1].z * kr.z + qr[1].w * kr.w;
                float s2 = qr[2].x * kr.x + qr[2].y * kr.y + qr[2].z * kr.z + qr[2].w * kr.w;
                float s3 = qr[3].x * kr.x + qr[3].y * kr.y + qr[3].z * kr.z + qr[3].w * kr.w;
#pragma unroll
                for (int msk = 16; msk >= 1; msk >>= 1) {
                    s0 += __shfl_xor(s0, msk);
                    s1 += __shfl_xor(s1, msk);
                    s2 += __shfl_xor(s2, msk);
                    s3 += __shfl_xor(s3, msk);
                }
                if (il < 4) {
                    float sel = s0;
                    if (il == 1) sel = s1;
                    if (il == 2) sel = s2;
                    if (il == 3) sel = s3;
                    sc[(t - clo) * 4 + il] = sel;
                }
                klo = klon; khi = khin; cs = csn;
            }
        }
        __syncthreads();

        // ================= block softmax over the chunk =================
        float pmax = -INFINITY;
        for (int tt = idxm; tt < cn; tt += 64) pmax = fmaxf(pmax, sc[tt * 4 + gsm]);
        pmax = fmaxf(pmax, __shfl_xor(pmax, 4));
        pmax = fmaxf(pmax, __shfl_xor(pmax, 8));
        pmax = fmaxf(pmax, __shfl_xor(pmax, 16));
        pmax = fmaxf(pmax, __shfl_xor(pmax, 32));
        if ((tid & 63) < 4) redM[w][tid & 3] = pmax;
        __syncthreads();

        const float Mn0 = fmaxf(Mr0, fmaxf(fmaxf(redM[0][0], redM[1][0]), fmaxf(redM[2][0], redM[3][0])));
        const float Mn1 = fmaxf(Mr1, fmaxf(fmaxf(redM[0][1], redM[1][1]), fmaxf(redM[2][1], redM[3][1])));
        const float Mn2 = fmaxf(Mr2, fmaxf(fmaxf(redM[0][2], redM[1][2]), fmaxf(redM[2][2], redM[3][2])));
        const float Mn3 = fmaxf(Mr3, fmaxf(fmaxf(redM[0][3], redM[1][3]), fmaxf(redM[2][3], redM[3][3])));

        const float Mg = (gsm == 0) ? Mn0 : (gsm == 1) ? Mn1 : (gsm == 2) ? Mn2 : Mn3;
        float lsum = 0.f;
        for (int tt = idxm; tt < cn; tt += 64) {
            float p = __expf(sc[tt * 4 + gsm] - Mg);
            sc[tt * 4 + gsm] = p;
            lsum += p;
        }
        lsum += __shfl_xor(lsum, 4);
        lsum += __shfl_xor(lsum, 8);
        lsum += __shfl_xor(lsum, 16);
        lsum += __shfl_xor(lsum, 32);
        if ((tid & 63) < 4) redL[w][tid & 3] = lsum;
        __syncthreads();

        {
            const float Lc0 = redL[0][0] + redL[1][0] + redL[2][0] + redL[3][0];
            const float Lc1 = redL[0][1] + redL[1][1] + redL[2][1] + redL[3][1];
            const float Lc2 = redL[0][2] + redL[1][2] + redL[2][2] + redL[3][2];
            const float Lc3 = redL[0][3] + redL[1][3] + redL[2][3] + redL[3][3];
            const float c0 = __expf(Mr0 - Mn0);   // first chunk: exp(-inf)=0
            const float c1 = __expf(Mr1 - Mn1);
            const float c2 = __expf(Mr2 - Mn2);
            const float c3 = __expf(Mr3 - Mn3);
            Lr0 = Lr0 * c0 + Lc0; o[0] *= c0; Mr0 = Mn0;
            Lr1 = Lr1 * c1 + Lc1; o[1] *= c1; Mr1 = Mn1;
            Lr2 = Lr2 * c2 + Lc2; o[2] *= c2; Mr2 = Mn2;
            Lr3 = Lr3 * c3 + Lc3; o[3] *= c3; Mr3 = Mn3;
        }

        // ================= phase 2: PV accumulation =================
        {
            int t = clo + hw;
            f4 vv = {}, vn = {};
            if (t < chi)
                vv = *(const f4*)(tok_base(vc, vcur, btrow, t, T, b, h) + d0v);
            if (t + 8 < chi)
                vn = *(const f4*)(tok_base(vc, vcur, btrow, t + 8, T, b, h) + d0v);
            for (; t < chi; t += 8) {
                f4 v2 = {};
                if (t + 16 < chi)
                    v2 = *(const f4*)(tok_base(vc, vcur, btrow, t + 16, T, b, h) + d0v);
                f4 p4 = *(const f4*)&sc[(t - clo) * 4];   // broadcast read
                o[0] += p4.x * vv;
                o[1] += p4.y * vv;
                o[2] += p4.z * vv;
                o[3] += p4.w * vv;
                vv = vn; vn = v2;
            }
        }
        __syncthreads();   // protect sc before next chunk's phase 1
    }

    // --- combine half-waves (plain sums: same M everywhere) ---
#pragma unroll
    for (int gg = 0; gg < 4; ++gg) {
        o[gg].x += __shfl_xor(o[gg].x, 32);
        o[gg].y += __shfl_xor(o[gg].y, 32);
        o[gg].z += __shfl_xor(o[gg].z, 32);
        o[gg].w += __shfl_xor(o[gg].w, 32);
    }
    if ((tid & 32) == 0) {
#pragma unroll
        for (int gg = 0; gg < 4; ++gg)
            *(f4*)(&lodata[w][gg][d0v]) = o[gg];
    }
    __syncthreads();

    {
        const int d  = tid & 127;
        const int g0 = tid >> 7;       // 0 or 1; handles heads g0 and g0+2
        const float LrA = (g0 == 0) ? Lr0 : Lr1;
        const float LrB = (g0 == 0) ? Lr2 : Lr3;
        const float MrA = (g0 == 0) ? Mr0 : Mr1;
        const float MrB = (g0 == 0) ? Mr2 : Mr3;

        float OA = lodata[0][g0][d] + lodata[1][g0][d] + lodata[2][g0][d] + lodata[3][g0][d];
        float OB = lodata[0][g0 + 2][d] + lodata[1][g0 + 2][d] + lodata[2][g0 + 2][d] + lodata[3][g0 + 2][d];

        if (S == 1) {
            out[(size_t)b * (NQH * HD) + (size_t)(h * GQA + g0) * HD + d]     = OA / LrA;
            out[(size_t)b * (NQH * HD) + (size_t)(h * GQA + g0 + 2) * HD + d] = OB / LrB;
        } else {
            int pidxA = blockIdx.x * 4 + g0;
            int pidxB = blockIdx.x * 4 + g0 + 2;
            po[(size_t)pidxA * HD + d] = OA;
            po[(size_t)pidxB * HD + d] = OB;
            if (d == 0) {
                pm[pidxA] = MrA; pl[pidxA] = LrA;
                pm[pidxB] = MrB; pl[pidxB] = LrB;
            }
        }
    }
}

__global__ void combine_kernel(
    const float* __restrict__ pm,
    const float* __restrict__ pl,
    const float* __restrict__ po,
    float* __restrict__ out, int S)
{
    int i = blockIdx.x * blockDim.x + threadIdx.x;   // over B*NQH*HD
    int d  = i & 127;
    int qh = (i >> 7) & 31;
    int b  = i >> 12;
    int h  = qh >> 2;
    int g  = qh & 3;
    int base = ((b * NKVH + h) * S) * 4 + g;
    float M = -INFINITY;
    for (int s = 0; s < S; ++s) M = fmaxf(M, pm[base + s * 4]);
    float L = 0.f, O = 0.f;
    for (int s = 0; s < S; ++s) {
        float wgt = __expf(pm[base + s * 4] - M);
        L += wgt * pl[base + s * 4];
        O += wgt * po[(size_t)(base + s * 4) * HD + d];
    }
    out[i] = O / L;
}

extern "C" void kernel_launch(void* const* d_in, const int* in_sizes, int n_in,
                              void* d_out, int out_size, void* d_ws, size_t ws_size,
                              hipStream_t stream) {
    const float* q  = (const float*)d_in[0];
    const float* k  = (const float*)d_in[1];
    const float* v  = (const float*)d_in[2];
    const float* kc = (const float*)d_in[3];
    const float* vc = (const float*)d_in[4];
    const int*   bt = (const int*)d_in[5];
    int B  = in_sizes[0] / (NQH * HD);
    int nb = in_sizes[5] / B;
    int T  = nb * PBLK;

    float* out = (float*)d_out;
    char*  ws  = (char*)d_ws;

    size_t tabBytes = (size_t)(T + 1) * 128 * sizeof(float);
    size_t off = (tabBytes + 255) & ~(size_t)255;

    int S = 8;
    int nblk = B * NKVH * S;
    size_t pmB = (size_t)nblk * 4 * sizeof(float);
    size_t poB = (size_t)nblk * 4 * HD * sizeof(float);
    size_t need = off + 2 * pmB + poB;

    int useTable = (ws_size >= tabBytes) ? 1 : 0;
    if (ws_size < need) S = 1;   // chunk loop handles long spans in-block

    float* tab = (float*)ws;
    float* pm  = (float*)(ws + off);
    float* pl  = (float*)(ws + off + pmB);
    float* po  = (float*)(ws + off + 2 * pmB);

    if (useTable) {
        int total = (T + 1) * 64;
        rope_table_kernel<<<(total + 255) / 256, 256, 0, stream>>>(tab, T);
    }
    paged_attn_kernel<<<B * NKVH * S, 256, 0, stream>>>(
        q, k, v, kc, vc, bt, tab, out, pm, pl, po, T, nb, S, useTable);
    if (S > 1) {
        int totalOut = B * NQH * HD;
        combine_kernel<<<(totalOut + 255) / 256, 256, 0, stream>>>(pm, pl, po, out, S);
    }
}